// Round 19
// baseline (73.895 us; speedup 1.0000x reference)
//
#include <hip/hip_runtime.h>
#include <hip/hip_bf16.h>

typedef __attribute__((ext_vector_type(16))) float f32x16;
typedef __attribute__((ext_vector_type(8)))  int   i32x8;
typedef __attribute__((ext_vector_type(4)))  int   i32x4;

static constexpr int NROW = 8192;
static constexpr int DDIM = 512;
static constexpr float INV_T = 10.0f;    // 1 / temperature
static constexpr float SHIFT = 70.0f;    // fixed logsumexp shift (logit max ~60)
// exp(acc*10 - 70) = exp2(acc*14.4269504 - 100.98865)
static constexpr float E2_SC = 14.4269504089f;
static constexpr float E2_BI = -100.988652759f;
static constexpr unsigned SCALE1 = 0x7F7F7F7Fu;   // e8m0 = 127 -> 2^0 = 1.0

__device__ __forceinline__ void gload_lds16(const void* gsrc, void* ldst) {
  __builtin_amdgcn_global_load_lds(
      (const __attribute__((address_space(1))) unsigned int*)gsrc,
      (__attribute__((address_space(3))) unsigned int*)ldst, 16, 0, 0);
}

// pack 4 floats into 4 fp8 e4m3 bytes (gfx950: OCP encoding)
__device__ __forceinline__ unsigned int pack_fp8x4(float x, float y, float z, float w) {
  unsigned int r = 0;
  r = __builtin_amdgcn_cvt_pk_fp8_f32(x, y, r, false);  // bytes 0,1
  r = __builtin_amdgcn_cvt_pk_fp8_f32(z, w, r, true);   // bytes 2,3
  return r;
}

// ---------- prep: normalize anchors, cast to fp8, EXACT fp32 diagonal ----------
__global__ void prep_kernel(const float* __restrict__ f0,
                            const float* __restrict__ f1,
                            unsigned int* __restrict__ A,   // [NROW][DDIM] fp8
                            unsigned int* __restrict__ B,
                            float* __restrict__ wsS,        // [NROW] exp-sums (zeroed)
                            float* __restrict__ wsPosRow) { // [NROW] exact pos_i
  int gid  = blockIdx.x * blockDim.x + threadIdx.x;
  if (gid < NROW) wsS[gid] = 0.f;             // zero LSE accumulators
  int wid  = gid >> 6;                         // one wave per row
  int lane = threadIdx.x & 63;
  const float4* s0 = (const float4*)(f0 + (size_t)wid * (2 * DDIM));  // features[:,0,:]
  const float4* s1 = (const float4*)(f1 + (size_t)wid * (2 * DDIM));  // features1[:,0,:]
  float4 v0 = s0[lane], v1 = s0[lane + 64];
  float4 w0 = s1[lane], w1 = s1[lane + 64];
  float ss = v0.x * v0.x + v0.y * v0.y + v0.z * v0.z + v0.w * v0.w +
             v1.x * v1.x + v1.y * v1.y + v1.z * v1.z + v1.w * v1.w;
  float cc = v0.x * w0.x + v0.y * w0.y + v0.z * w0.z + v0.w * w0.w +
             v1.x * w1.x + v1.y * w1.y + v1.z * w1.z + v1.w * w1.w;
#pragma unroll
  for (int m = 1; m < 64; m <<= 1) {
    ss += __shfl_xor(ss, m);
    cc += __shfl_xor(cc, m);
  }
  float rn = rsqrtf(ss);
  if (lane == 0) wsPosRow[wid] = cc * rn * INV_T;   // exact fp32 diagonal logit
  A[wid * 128 + lane]      = pack_fp8x4(v0.x * rn, v0.y * rn, v0.z * rn, v0.w * rn);
  A[wid * 128 + 64 + lane] = pack_fp8x4(v1.x * rn, v1.y * rn, v1.z * rn, v1.w * rn);
  B[wid * 128 + lane]      = pack_fp8x4(w0.x, w0.y, w0.z, w0.w);
  B[wid * 128 + 64 + lane] = pack_fp8x4(w1.x, w1.y, w1.z, w1.w);
}

// ---------- fused S = A.B^T / T with fixed-shift LSE accumulation ----------
// MX-scaled fp8 32x32x64 (scales = 1.0 == plain fp8 numerics; verified r11).
// (256,1): the only config this compiler grants the 256-VGPR class (r6-r18).
// 4-CHAIN ILP: all four accumulators (jb0/jb1 x row-block0/1) live through the
// ks loop; each ks issues 2 B-loads + 4 independent MFMAs -> dependency
// distance 4x64 = 256 issue-cyc >= scale-MFMA latency, so the chains never
// stall even at 1 wave/SIMD (r18 evidence: occupancy ~10% = no TLP; its
// 2-chain version had distance 128 ~ latency -> exposed stalls, MfmaUtil 22%).
// grid 512 x 256 thr; LDS dbuf 2x32 KiB; staging swizzle verbatim r8.
__global__ __launch_bounds__(256, 1) void sim_lse_kernel(
    const unsigned char* __restrict__ Ag,
    const unsigned char* __restrict__ Bg,
    float* __restrict__ wsS) {
  __shared__ __align__(16) char bufA[64 * 512];   // 32 KiB, tiles 0,2,4,...
  __shared__ __align__(16) char bufB[64 * 512];   // 32 KiB, tiles 1,3,5,...

  const int tid  = threadIdx.x;
  const int w    = tid >> 6;                 // wave 0..3
  const int lane = tid & 63;
  const int lr5  = lane & 31;                // row (A) / col (B,D) within 32
  const int h    = lane >> 5;                // k-half selector (32 B each)

  const int p  = blockIdx.x >> 4;            // row panel 0..31 (256 rows)
  const int cs = blockIdx.x & 15;            // col split 0..15 (512 cols)
  const int r0 = p * 256 + w * 64;           // this wave's first row (64 rows)
  const int c0 = cs * 512;                   // first column of this split

  // staging: 8 iters; iter it stages row-pair pr = it*4 + w (rows 2pr+h);
  // src byte ((lane&31)<<4) ^ ((n&7)<<4), n&7 = (2w+h)&7 -> per-thread const.
  const int stg_off = ((lane & 31) << 4) ^ (((2 * w + h) & 7) << 4);
  const int stg_row = h;

  // A fragments, K-resident, 2 row-blocks:
  // aX[ks] = 32 B of A[r0+X*32+lr5][ks*64 + h*32 .. +32)
  i32x8 a0[8], a1[8];
  {
    const char* ar0 = (const char*)Ag + (size_t)(r0 + lr5) * DDIM + h * 32;
    const char* ar1 = (const char*)Ag + (size_t)(r0 + 32 + lr5) * DDIM + h * 32;
#pragma unroll
    for (int ks = 0; ks < 8; ks++) {
      a0[ks] = *(const i32x8*)(ar0 + ks * 64);
      a1[ks] = *(const i32x8*)(ar1 + ks * 64);
    }
  }

  float sums0[16], sums1[16];
#pragma unroll
  for (int r = 0; r < 16; r++) { sums0[r] = 0.f; sums1[r] = 0.f; }

#define STAGE(BUF, T)                                                          \
  {                                                                            \
    const char* gb = (const char*)Bg + (size_t)(c0 + (T) * 64) * DDIM;         \
    _Pragma("unroll")                                                          \
    for (int it = 0; it < 8; it++) {                                           \
      int pr = it * 4 + w;                                                     \
      gload_lds16(gb + (size_t)(2 * pr + stg_row) * DDIM + stg_off,            \
                  (char*)(BUF) + pr * 1024);                                   \
    }                                                                          \
  }

// One tile: 4 interleaved MFMA chains (jb0/jb1 x rb0/rb1), epilogue after.
#define MFMA_EPI(BUF, T)                                                       \
  {                                                                            \
    const int swz = (lr5 & 7) << 4;                                            \
    f32x16 acc00 = (f32x16){0.f};   /* rb0 x jb0 */                            \
    f32x16 acc01 = (f32x16){0.f};   /* rb0 x jb1 */                            \
    f32x16 acc10 = (f32x16){0.f};   /* rb1 x jb0 */                            \
    f32x16 acc11 = (f32x16){0.f};   /* rb1 x jb1 */                            \
    _Pragma("unroll")                                                          \
    for (int ks = 0; ks < 8; ks++) {                                           \
      const int b0 = ((lr5) * 512 + ks * 64 + h * 32) ^ swz;        /* jb0 */  \
      const int b1 = ((32 + lr5) * 512 + ks * 64 + h * 32) ^ swz;   /* jb1 */  \
      i32x4 q00 = *(const i32x4*)((const char*)(BUF) + b0);                    \
      i32x4 q01 = *(const i32x4*)((const char*)(BUF) + (b0 ^ 16));             \
      i32x4 q10 = *(const i32x4*)((const char*)(BUF) + b1);                    \
      i32x4 q11 = *(const i32x4*)((const char*)(BUF) + (b1 ^ 16));             \
      i32x8 bv0 = __builtin_shufflevector(q00, q01, 0, 1, 2, 3, 4, 5, 6, 7);   \
      i32x8 bv1 = __builtin_shufflevector(q10, q11, 0, 1, 2, 3, 4, 5, 6, 7);   \
      acc00 = __builtin_amdgcn_mfma_scale_f32_32x32x64_f8f6f4(                 \
          a0[ks], bv0, acc00, 0, 0, 0, SCALE1, 0, SCALE1);                     \
      acc10 = __builtin_amdgcn_mfma_scale_f32_32x32x64_f8f6f4(                 \
          a1[ks], bv0, acc10, 0, 0, 0, SCALE1, 0, SCALE1);                     \
      acc01 = __builtin_amdgcn_mfma_scale_f32_32x32x64_f8f6f4(                 \
          a0[ks], bv1, acc01, 0, 0, 0, SCALE1, 0, SCALE1);                     \
      acc11 = __builtin_amdgcn_mfma_scale_f32_32x32x64_f8f6f4(                 \
          a1[ks], bv1, acc11, 0, 0, 0, SCALE1, 0, SCALE1);                     \
    }                                                                          \
    _Pragma("unroll")                                                          \
    for (int r = 0; r < 16; r++) {                                             \
      sums0[r] += exp2f(fmaf(acc00[r], E2_SC, E2_BI)) +                        \
                  exp2f(fmaf(acc01[r], E2_SC, E2_BI));                         \
      sums1[r] += exp2f(fmaf(acc10[r], E2_SC, E2_BI)) +                        \
                  exp2f(fmaf(acc11[r], E2_SC, E2_BI));                         \
    }                                                                          \
  }

  STAGE(bufA, 0);
  __syncthreads();                            // tile 0 ready

#pragma unroll 1
  for (int t = 0; t < 8; t += 2) {
    STAGE(bufB, t + 1);                       // async; lands under MFMA below
    MFMA_EPI(bufA, t);                        // tile t
    __syncthreads();                          // readers of A done; B drained
    if (t + 2 < 8) STAGE(bufA, t + 2);        // async; lands under MFMA below
    MFMA_EPI(bufB, t + 1);                    // tile t+1
    __syncthreads();
  }

#undef STAGE
#undef MFMA_EPI

  // reduce over the 32 col-partition lanes; lanes lr5==0 (h=0,1) commit rows
#pragma unroll
  for (int r = 0; r < 16; r++) {
    float s0 = sums0[r], s1 = sums1[r];
    s0 += __shfl_xor(s0, 1);  s1 += __shfl_xor(s1, 1);
    s0 += __shfl_xor(s0, 2);  s1 += __shfl_xor(s1, 2);
    s0 += __shfl_xor(s0, 4);  s1 += __shfl_xor(s1, 4);
    s0 += __shfl_xor(s0, 8);  s1 += __shfl_xor(s1, 8);
    s0 += __shfl_xor(s0, 16); s1 += __shfl_xor(s1, 16);
    if (lr5 == 0) {
      int rr = (r & 3) + 8 * (r >> 2) + 4 * h;
      atomicAdd(&wsS[r0 + rr], s0);
      atomicAdd(&wsS[r0 + 32 + rr], s1);
    }
  }
}

// ---------- finalize: loss = mean(SHIFT + log(S_r) - pos_r) ----------
__global__ void finalize_kernel(const float* __restrict__ wsS,
                                const float* __restrict__ wsPosRow,
                                float* __restrict__ out) {
  __shared__ float red[16];
  float part = 0.f;
  for (int r = threadIdx.x; r < NROW; r += 1024)
    part += SHIFT + __logf(wsS[r]) - wsPosRow[r];
#pragma unroll
  for (int m = 1; m < 64; m <<= 1) part += __shfl_xor(part, m);
  if ((threadIdx.x & 63) == 0) red[threadIdx.x >> 6] = part;
  __syncthreads();
  if (threadIdx.x < 16) {
    float t = red[threadIdx.x];
#pragma unroll
    for (int m = 1; m < 16; m <<= 1) t += __shfl_xor(t, m);
    if (threadIdx.x == 0) out[0] = t / (float)NROW;
  }
}

extern "C" void kernel_launch(void* const* d_in, const int* in_sizes, int n_in,
                              void* d_out, int out_size, void* d_ws, size_t ws_size,
                              hipStream_t stream) {
  const float* f0 = (const float*)d_in[0];
  const float* f1 = (const float*)d_in[1];
  // d_in[2] (y) is unused by the reference computation.

  unsigned char* A = (unsigned char*)d_ws;                         // 4 MiB fp8
  unsigned char* B = A + (size_t)NROW * DDIM;                      // 4 MiB fp8
  float* wsS      = (float*)(B + (size_t)NROW * DDIM);             // [NROW]
  float* wsPosRow = wsS + NROW;                                    // [NROW]

  prep_kernel<<<NROW / 4, 256, 0, stream>>>(f0, f1, (unsigned int*)A,
                                            (unsigned int*)B, wsS, wsPosRow);
  sim_lse_kernel<<<512, 256, 0, stream>>>(A, B, wsS);
  finalize_kernel<<<1, 1024, 0, stream>>>(wsS, wsPosRow, (float*)d_out);
}

// Round 20
// 63.371 us; speedup vs baseline: 1.1661x; 1.1661x over previous
//
#include <hip/hip_runtime.h>
#include <hip/hip_bf16.h>

typedef __attribute__((ext_vector_type(16))) float f32x16;
typedef __attribute__((ext_vector_type(8)))  int   i32x8;
typedef __attribute__((ext_vector_type(4)))  int   i32x4;

static constexpr int NROW = 8192;
static constexpr int DDIM = 512;
static constexpr float INV_T = 10.0f;    // 1 / temperature
static constexpr float SHIFT = 70.0f;    // fixed logsumexp shift (logit max ~60)
// exp(acc*10 - 70) = exp2(acc*14.4269504 - 100.98865)
static constexpr float E2_SC = 14.4269504089f;
static constexpr float E2_BI = -100.988652759f;
static constexpr unsigned SCALE1 = 0x7F7F7F7Fu;   // e8m0 = 127 -> 2^0 = 1.0

__device__ __forceinline__ void gload_lds16(const void* gsrc, void* ldst) {
  __builtin_amdgcn_global_load_lds(
      (const __attribute__((address_space(1))) unsigned int*)gsrc,
      (__attribute__((address_space(3))) unsigned int*)ldst, 16, 0, 0);
}

// single-instruction v_exp_f32 (arg range here is [-187,-14]: no edge cases)
__device__ __forceinline__ float fast_exp2(float x) {
#if __has_builtin(__builtin_amdgcn_exp2f)
  return __builtin_amdgcn_exp2f(x);
#else
  float r;
  asm("v_exp_f32 %0, %1" : "=v"(r) : "v"(x));
  return r;
#endif
}

// pack 4 floats into 4 fp8 e4m3 bytes (gfx950: OCP encoding)
__device__ __forceinline__ unsigned int pack_fp8x4(float x, float y, float z, float w) {
  unsigned int r = 0;
  r = __builtin_amdgcn_cvt_pk_fp8_f32(x, y, r, false);  // bytes 0,1
  r = __builtin_amdgcn_cvt_pk_fp8_f32(z, w, r, true);   // bytes 2,3
  return r;
}

// ---------- prep: normalize anchors, cast to fp8, EXACT fp32 diagonal ----------
__global__ void prep_kernel(const float* __restrict__ f0,
                            const float* __restrict__ f1,
                            unsigned int* __restrict__ A,   // [NROW][DDIM] fp8
                            unsigned int* __restrict__ B,
                            float* __restrict__ wsS,        // [NROW] exp-sums (zeroed)
                            float* __restrict__ wsPosRow) { // [NROW] exact pos_i
  int gid  = blockIdx.x * blockDim.x + threadIdx.x;
  if (gid < NROW) wsS[gid] = 0.f;             // zero LSE accumulators
  int wid  = gid >> 6;                         // one wave per row
  int lane = threadIdx.x & 63;
  const float4* s0 = (const float4*)(f0 + (size_t)wid * (2 * DDIM));  // features[:,0,:]
  const float4* s1 = (const float4*)(f1 + (size_t)wid * (2 * DDIM));  // features1[:,0,:]
  float4 v0 = s0[lane], v1 = s0[lane + 64];
  float4 w0 = s1[lane], w1 = s1[lane + 64];
  float ss = v0.x * v0.x + v0.y * v0.y + v0.z * v0.z + v0.w * v0.w +
             v1.x * v1.x + v1.y * v1.y + v1.z * v1.z + v1.w * v1.w;
  float cc = v0.x * w0.x + v0.y * w0.y + v0.z * w0.z + v0.w * w0.w +
             v1.x * w1.x + v1.y * w1.y + v1.z * w1.z + v1.w * w1.w;
#pragma unroll
  for (int m = 1; m < 64; m <<= 1) {
    ss += __shfl_xor(ss, m);
    cc += __shfl_xor(cc, m);
  }
  float rn = rsqrtf(ss);
  if (lane == 0) wsPosRow[wid] = cc * rn * INV_T;   // exact fp32 diagonal logit
  A[wid * 128 + lane]      = pack_fp8x4(v0.x * rn, v0.y * rn, v0.z * rn, v0.w * rn);
  A[wid * 128 + 64 + lane] = pack_fp8x4(v1.x * rn, v1.y * rn, v1.z * rn, v1.w * rn);
  B[wid * 128 + lane]      = pack_fp8x4(w0.x, w0.y, w0.z, w0.w);
  B[wid * 128 + 64 + lane] = pack_fp8x4(w1.x, w1.y, w1.z, w1.w);
}

// ---------- fused S = A.B^T / T with fixed-shift LSE accumulation ----------
// r18 structure verbatim (best: 60 us) + VALU trim:
//  * ds_read addresses decomposed into 4 per-jb base pointers + m*128
//    compile-time offsets (the XOR swizzle only touches bits 4-6, which are
//    carry-free vs ks*64/m*128 -> exact decomposition, zero inner addr VALU).
//  * fast_exp2 = raw v_exp_f32 (libcall exp2f lowers fat without fast-math;
//    arg range [-187,-14] needs no special-case handling).
//  * s_setprio(1) around the MFMA cluster (T5).
// MX-scaled fp8 32x32x64, scales=1.0 (== plain fp8 numerics, verified r11).
// (256,1): the only config granted the 256-VGPR class (r6-r17 evidence).
__global__ __launch_bounds__(256, 1) void sim_lse_kernel(
    const unsigned char* __restrict__ Ag,
    const unsigned char* __restrict__ Bg,
    float* __restrict__ wsS) {
  __shared__ __align__(16) char bufA[64 * 512];   // 32 KiB, tiles 0,2,4,...
  __shared__ __align__(16) char bufB[64 * 512];   // 32 KiB, tiles 1,3,5,...

  const int tid  = threadIdx.x;
  const int w    = tid >> 6;                 // wave 0..3
  const int lane = tid & 63;
  const int lr5  = lane & 31;                // row (A) / col (B,D) within 32
  const int h    = lane >> 5;                // k-half selector (32 B each)

  const int p  = blockIdx.x >> 4;            // row panel 0..31 (256 rows)
  const int cs = blockIdx.x & 15;            // col split 0..15 (512 cols)
  const int r0 = p * 256 + w * 64;           // this wave's first row (64 rows)
  const int c0 = cs * 512;                   // first column of this split

  // staging: 8 iters; iter it stages row-pair pr = it*4 + w (rows 2pr+h);
  // src byte ((lane&31)<<4) ^ ((n&7)<<4), n&7 = (2w+h)&7 -> per-thread const.
  const int stg_off = ((lane & 31) << 4) ^ (((2 * w + h) & 7) << 4);
  const int stg_row = h;

  // A fragments, K-resident, 2 row-blocks:
  // aX[ks] = 32 B of A[r0+X*32+lr5][ks*64 + h*32 .. +32)
  i32x8 a0[8], a1[8];
  {
    const char* ar0 = (const char*)Ag + (size_t)(r0 + lr5) * DDIM + h * 32;
    const char* ar1 = (const char*)Ag + (size_t)(r0 + 32 + lr5) * DDIM + h * 32;
#pragma unroll
    for (int ks = 0; ks < 8; ks++) {
      a0[ks] = *(const i32x8*)(ar0 + ks * 64);
      a1[ks] = *(const i32x8*)(ar1 + ks * 64);
    }
  }

  float sums0[16], sums1[16];
#pragma unroll
  for (int r = 0; r < 16; r++) { sums0[r] = 0.f; sums1[r] = 0.f; }

#define STAGE(BUF, T)                                                          \
  {                                                                            \
    const char* gb = (const char*)Bg + (size_t)(c0 + (T) * 64) * DDIM;         \
    _Pragma("unroll")                                                          \
    for (int it = 0; it < 8; it++) {                                           \
      int pr = it * 4 + w;                                                     \
      gload_lds16(gb + (size_t)(2 * pr + stg_row) * DDIM + stg_off,            \
                  (char*)(BUF) + pr * 1024);                                   \
    }                                                                          \
  }

// One tile: per jb, one B-fragment stream feeds two MFMA chains (row-blocks).
// ks = 2m+e: addr = base_e + m*128 (exact; see header comment).
#define MFMA_EPI(BUF, T)                                                       \
  {                                                                            \
    const int swz = (lr5 & 7) << 4;                                            \
    _Pragma("unroll")                                                          \
    for (int jb = 0; jb < 2; jb++) {                                           \
      const int cb = ((jb * 32 + lr5) * 512 + h * 32) ^ swz;                   \
      const char* p0  = (const char*)(BUF) + cb;                               \
      const char* p0x = (const char*)(BUF) + (cb ^ 16);                        \
      const char* p1  = (const char*)(BUF) + (cb ^ 64);                        \
      const char* p1x = (const char*)(BUF) + (cb ^ 80);                        \
      f32x16 acc0 = (f32x16){0.f};                                             \
      f32x16 acc1 = (f32x16){0.f};                                             \
      __builtin_amdgcn_s_setprio(1);                                           \
      _Pragma("unroll")                                                        \
      for (int m = 0; m < 4; m++) {                                            \
        i32x8 bvE = __builtin_shufflevector(                                   \
            *(const i32x4*)(p0 + m * 128), *(const i32x4*)(p0x + m * 128),     \
            0, 1, 2, 3, 4, 5, 6, 7);                                           \
        i32x8 bvO = __builtin_shufflevector(                                   \
            *(const i32x4*)(p1 + m * 128), *(const i32x4*)(p1x + m * 128),     \
            0, 1, 2, 3, 4, 5, 6, 7);                                           \
        acc0 = __builtin_amdgcn_mfma_scale_f32_32x32x64_f8f6f4(                \
            a0[2 * m], bvE, acc0, 0, 0, 0, SCALE1, 0, SCALE1);                 \
        acc1 = __builtin_amdgcn_mfma_scale_f32_32x32x64_f8f6f4(                \
            a1[2 * m], bvE, acc1, 0, 0, 0, SCALE1, 0, SCALE1);                 \
        acc0 = __builtin_amdgcn_mfma_scale_f32_32x32x64_f8f6f4(                \
            a0[2 * m + 1], bvO, acc0, 0, 0, 0, SCALE1, 0, SCALE1);             \
        acc1 = __builtin_amdgcn_mfma_scale_f32_32x32x64_f8f6f4(                \
            a1[2 * m + 1], bvO, acc1, 0, 0, 0, SCALE1, 0, SCALE1);             \
      }                                                                        \
      __builtin_amdgcn_s_setprio(0);                                           \
      _Pragma("unroll")                                                        \
      for (int r = 0; r < 16; r++) {                                           \
        sums0[r] += fast_exp2(fmaf(acc0[r], E2_SC, E2_BI));                    \
        sums1[r] += fast_exp2(fmaf(acc1[r], E2_SC, E2_BI));                    \
      }                                                                        \
    }                                                                          \
  }

  STAGE(bufA, 0);
  __syncthreads();                            // tile 0 ready

#pragma unroll 1
  for (int t = 0; t < 8; t += 2) {
    STAGE(bufB, t + 1);                       // async; lands under MFMA below
    MFMA_EPI(bufA, t);                        // tile t
    __syncthreads();                          // readers of A done; B drained
    if (t + 2 < 8) STAGE(bufA, t + 2);        // async; lands under MFMA below
    MFMA_EPI(bufB, t + 1);                    // tile t+1
    __syncthreads();
  }

#undef STAGE
#undef MFMA_EPI

  // reduce over the 32 col-partition lanes; lanes lr5==0 (h=0,1) commit rows
#pragma unroll
  for (int r = 0; r < 16; r++) {
    float s0 = sums0[r], s1 = sums1[r];
    s0 += __shfl_xor(s0, 1);  s1 += __shfl_xor(s1, 1);
    s0 += __shfl_xor(s0, 2);  s1 += __shfl_xor(s1, 2);
    s0 += __shfl_xor(s0, 4);  s1 += __shfl_xor(s1, 4);
    s0 += __shfl_xor(s0, 8);  s1 += __shfl_xor(s1, 8);
    s0 += __shfl_xor(s0, 16); s1 += __shfl_xor(s1, 16);
    if (lr5 == 0) {
      int rr = (r & 3) + 8 * (r >> 2) + 4 * h;
      atomicAdd(&wsS[r0 + rr], s0);
      atomicAdd(&wsS[r0 + 32 + rr], s1);
    }
  }
}

// ---------- finalize: loss = mean(SHIFT + log(S_r) - pos_r) ----------
__global__ void finalize_kernel(const float* __restrict__ wsS,
                                const float* __restrict__ wsPosRow,
                                float* __restrict__ out) {
  __shared__ float red[16];
  float part = 0.f;
  for (int r = threadIdx.x; r < NROW; r += 1024)
    part += SHIFT + __logf(wsS[r]) - wsPosRow[r];
#pragma unroll
  for (int m = 1; m < 64; m <<= 1) part += __shfl_xor(part, m);
  if ((threadIdx.x & 63) == 0) red[threadIdx.x >> 6] = part;
  __syncthreads();
  if (threadIdx.x < 16) {
    float t = red[threadIdx.x];
#pragma unroll
    for (int m = 1; m < 16; m <<= 1) t += __shfl_xor(t, m);
    if (threadIdx.x == 0) out[0] = t / (float)NROW;
  }
}

extern "C" void kernel_launch(void* const* d_in, const int* in_sizes, int n_in,
                              void* d_out, int out_size, void* d_ws, size_t ws_size,
                              hipStream_t stream) {
  const float* f0 = (const float*)d_in[0];
  const float* f1 = (const float*)d_in[1];
  // d_in[2] (y) is unused by the reference computation.

  unsigned char* A = (unsigned char*)d_ws;                         // 4 MiB fp8
  unsigned char* B = A + (size_t)NROW * DDIM;                      // 4 MiB fp8
  float* wsS      = (float*)(B + (size_t)NROW * DDIM);             // [NROW]
  float* wsPosRow = wsS + NROW;                                    // [NROW]

  prep_kernel<<<NROW / 4, 256, 0, stream>>>(f0, f1, (unsigned int*)A,
                                            (unsigned int*)B, wsS, wsPosRow);
  sim_lse_kernel<<<512, 256, 0, stream>>>(A, B, wsS);
  finalize_kernel<<<1, 1024, 0, stream>>>(wsS, wsPosRow, (float*)d_out);
}